// Round 5
// baseline (325.811 us; speedup 1.0000x reference)
//
#include <hip/hip_runtime.h>
#include <stdint.h>

typedef __attribute__((ext_vector_type(8))) short short8;
typedef __attribute__((ext_vector_type(4))) float floatx4;

// ---------- helpers ----------
__device__ __forceinline__ float bf16_to_f(uint16_t u) {
    union { uint32_t i; float f; } v; v.i = ((uint32_t)u) << 16; return v.f;
}
__device__ __forceinline__ uint16_t f_to_bf16(float f) {
    union { uint32_t i; float f; } v; v.f = f;
    uint32_t u = v.i;
    u += 0x7FFFu + ((u >> 16) & 1u);   // round-to-nearest-even
    return (uint16_t)(u >> 16);
}
__device__ __forceinline__ void gload16(const void* g, void* l) {
    __builtin_amdgcn_global_load_lds(
        (const __attribute__((address_space(1))) void*)g,
        (__attribute__((address_space(3))) void*)l, 16, 0, 0);
}
__device__ __forceinline__ float rcpf(float x) { return __builtin_amdgcn_rcpf(x); }

// LDS-only barrier: waits own LDS ops, does NOT drain vmcnt.
__device__ __forceinline__ void bar_lds() {
    asm volatile("s_waitcnt lgkmcnt(0)" ::: "memory");
    __builtin_amdgcn_s_barrier();
    asm volatile("" ::: "memory");
}

#define B_  32
#define T_  512
#define CF_ 2048
#define H_  128
#define G4_ 512   // 4*H
#define LOG2E 1.4426950408889634f

// =====================================================================
// k_cvt_all: all 6 weight tensors fp32 -> bf16 in ONE launch.
// =====================================================================
__global__ __launch_bounds__(256) void k_cvt_all(
        const float* __restrict__ Wfc, const float* __restrict__ Wih_f,
        const float* __restrict__ Wih_b, const float* __restrict__ Whh_f,
        const float* __restrict__ Whh_b, const float* __restrict__ Wout,
        uint16_t* __restrict__ WfcB, uint16_t* __restrict__ WihB,
        uint16_t* __restrict__ WhhB, uint16_t* __restrict__ WoutB) {
    const int blk = blockIdx.x;
    const float* s; uint16_t* d; int off;
    if (blk < 256)      { s = Wfc;   d = WfcB;          off = blk; }
    else if (blk < 320) { s = Wih_f; d = WihB;          off = blk - 256; }
    else if (blk < 384) { s = Wih_b; d = WihB + 65536;  off = blk - 320; }
    else if (blk < 448) { s = Whh_f; d = WhhB;          off = blk - 384; }
    else if (blk < 512) { s = Whh_b; d = WhhB + 65536;  off = blk - 448; }
    else                { s = Wout;  d = WoutB;         off = blk - 512; }
    const int i = off * 1024 + threadIdx.x * 4;
    float4 v = *(const float4*)&s[i];
    ushort4 o;
    o.x = f_to_bf16(v.x); o.y = f_to_bf16(v.y);
    o.z = f_to_bf16(v.z); o.w = f_to_bf16(v.w);
    *(ushort4*)&d[i] = o;
}

// =====================================================================
// k_xt: streaming transpose + cast.  x[b][cf][t] fp32 -> xT[b][t][cf] bf16.
// 64x64 tiles, 256 thr, grid (8 t-tiles, 32 cf-tiles, 32 b) = 8192 blocks
// (~8 resident blocks/CU -> latency-tolerant, streams near HBM BW).
// =====================================================================
__global__ __launch_bounds__(256) void k_xt(const float* __restrict__ x,
                                            uint16_t* __restrict__ xT) {
    __shared__ uint16_t tl[64][72];    // [t][cf], stride 144 B (16B-aligned)
    const int b = blockIdx.z, cf0 = blockIdx.y * 64, t0 = blockIdx.x * 64;
    const int tid = threadIdx.x;
    const int t4 = (tid & 15) * 4, cfr = tid >> 4;     // cfr 0..15
    #pragma unroll
    for (int pass = 0; pass < 4; ++pass) {
        const int cf = cfr + pass * 16;
        const float4 v = *(const float4*)
            &x[(size_t)(b * CF_ + cf0 + cf) * T_ + t0 + t4];
        tl[t4 + 0][cf] = f_to_bf16(v.x);
        tl[t4 + 1][cf] = f_to_bf16(v.y);
        tl[t4 + 2][cf] = f_to_bf16(v.z);
        tl[t4 + 3][cf] = f_to_bf16(v.w);
    }
    __syncthreads();
    const int tr = tid >> 2;
    #pragma unroll
    for (int pass = 0; pass < 2; ++pass) {
        const int cfo = ((tid & 3) + 4 * pass) * 8;
        *(short8*)&xT[(size_t)(b * T_ + t0 + tr) * CF_ + cf0 + cfo] =
            *(const short8*)&tl[tr][cfo];
    }
}

// =====================================================================
// k_fc1g: fc1 + input-projection, ALL staging via global_load_lds.
// B-tile comes straight from pre-transposed xT (bf16) -> no fp32 tile,
// no scalar LDS transpose, no converts in the hot loop.
// Grid (8, 32), 512 thr. Loop: sync; 3 gloads/wave; sync; frags+MFMA.
// =====================================================================
__global__ __launch_bounds__(512) void k_fc1g(const uint16_t* __restrict__ xT,
                                              const uint16_t* __restrict__ WfcB,
                                              const float* __restrict__ bfc,
                                              const uint16_t* __restrict__ WihB,
                                              const float* __restrict__ b_f,
                                              const float* __restrict__ b_b,
                                              uint16_t* __restrict__ Xp) {
    __shared__ __align__(16) uint16_t As[8192];        // W chunk-major
    __shared__ __align__(16) uint16_t Bs[4224];        // xT chunk-major (stride 66)
    __shared__ __align__(16) uint16_t Hs2[8432];       // Hfc chunk-major (stride 66)

    const int bb = blockIdx.y, n0 = blockIdx.x * 64;
    const int tid = threadIdx.x, w = tid >> 6, l = tid & 63;
    const int lm = l & 15, lk = l >> 4;
    const uint16_t* xTb = xT + (size_t)bb * T_ * CF_;

    // ---------------- Phase A ----------------
    const int wmA = (w >> 1) * 32, wnA = (w & 1) * 32;
    floatx4 acc[2][2] = {};
    for (int k0 = 0; k0 < CF_; k0 += 64) {
        __syncthreads();   // protect As/Bs against previous iter's frag reads
        // A staging: wave w stages chunk w (k-offset w*8), rows l and 64+l
        gload16(WfcB + (size_t)l * CF_ + k0 + w * 8,        As + (w * 128 + l) * 8);
        gload16(WfcB + (size_t)(64 + l) * CF_ + k0 + w * 8, As + (w * 128 + 64 + l) * 8);
        // B staging: wave w stages chunk w, lane l = t-slot
        gload16(xTb + (size_t)(n0 + l) * CF_ + k0 + w * 8,  Bs + (w * 66 + l) * 8);
        __syncthreads();   // drains vmcnt(0): all staging visible
        // frags + MFMA
        short8 a[2][2], bfr[2][2];
        #pragma unroll
        for (int kf = 0; kf < 2; ++kf) {
            #pragma unroll
            for (int mf = 0; mf < 2; ++mf)
                a[mf][kf] = *(const short8*)&As[((kf * 4 + lk) * 128 + wmA + mf * 16 + lm) * 8];
            #pragma unroll
            for (int nf = 0; nf < 2; ++nf)
                bfr[nf][kf] = *(const short8*)&Bs[((kf * 4 + lk) * 66 + wnA + nf * 16 + lm) * 8];
        }
        #pragma unroll
        for (int mf = 0; mf < 2; ++mf)
            #pragma unroll
            for (int nf = 0; nf < 2; ++nf) {
                acc[mf][nf] = __builtin_amdgcn_mfma_f32_16x16x32_bf16(a[mf][0], bfr[nf][0], acc[mf][nf], 0, 0, 0);
                acc[mf][nf] = __builtin_amdgcn_mfma_f32_16x16x32_bf16(a[mf][1], bfr[nf][1], acc[mf][nf], 0, 0, 0);
            }
    }
    __syncthreads();
    // epilogue A: bias + bf16 -> Hs2 chunk-major (stride 66)
    #pragma unroll
    for (int mf = 0; mf < 2; ++mf) {
        const int d0 = wmA + mf * 16 + lk * 4;
        const float4 bv = *(const float4*)&bfc[d0];
        const int c = ((wmA + mf * 16) >> 3) + (lk >> 1);
        #pragma unroll
        for (int nf = 0; nf < 2; ++nf) {
            const int t = wnA + nf * 16 + lm;
            ushort4 o;
            o.x = f_to_bf16(acc[mf][nf][0] + bv.x);
            o.y = f_to_bf16(acc[mf][nf][1] + bv.y);
            o.z = f_to_bf16(acc[mf][nf][2] + bv.z);
            o.w = f_to_bf16(acc[mf][nf][3] + bv.w);
            *(ushort4*)&Hs2[(c * 66 + t) * 8 + (lk & 1) * 4] = o;
        }
    }
    __syncthreads();

    // ---------------- Phase B ----------------
    const int dirw = w >> 2;
    const int db   = dirw * B_ + bb;
    const uint16_t* Wp = WihB + (size_t)dirw * (G4_ * H_);
    const float* bi = dirw ? b_b : b_f;
    #pragma unroll
    for (int it = 0; it < 2; ++it) {
        const int gbase = (w & 3) * 64 + it * 256;
        short8 aw[4][4];
        #pragma unroll
        for (int mf = 0; mf < 4; ++mf)
            #pragma unroll
            for (int kf = 0; kf < 4; ++kf)
                aw[mf][kf] = *(const short8*)&Wp[(size_t)(gbase + mf * 16 + lm) * H_ + kf * 32 + lk * 8];
        floatx4 acc2[4][4] = {};
        #pragma unroll
        for (int nf = 0; nf < 4; ++nf) {
            short8 bbf[4];
            #pragma unroll
            for (int kf = 0; kf < 4; ++kf)
                bbf[kf] = *(const short8*)&Hs2[((kf * 4 + lk) * 66 + nf * 16 + lm) * 8];
            #pragma unroll
            for (int mf = 0; mf < 4; ++mf)
                #pragma unroll
                for (int kf = 0; kf < 4; ++kf)
                    acc2[mf][nf] = __builtin_amdgcn_mfma_f32_16x16x32_bf16(aw[mf][kf], bbf[kf], acc2[mf][nf], 0, 0, 0);
        }
        #pragma unroll
        for (int mf = 0; mf < 4; ++mf) {
            const int g0 = gbase + mf * 16 + lk * 4;
            const float4 bv = *(const float4*)&bi[g0];
            #pragma unroll
            for (int nf = 0; nf < 4; ++nf) {
                const int t = n0 + nf * 16 + lm;
                ushort4 o;
                o.x = f_to_bf16(acc2[mf][nf][0] + bv.x);
                o.y = f_to_bf16(acc2[mf][nf][1] + bv.y);
                o.z = f_to_bf16(acc2[mf][nf][2] + bv.z);
                o.w = f_to_bf16(acc2[mf][nf][3] + bv.w);
                *(ushort4*)&Xp[((size_t)db * T_ + t) * G4_ + g0] = o;
            }
        }
    }
}

// =====================================================================
// k_fc1x: FALLBACK fused version (round-0 structure) — used only when
// ws_size cannot hold xT.
// =====================================================================
__global__ __launch_bounds__(512) void k_fc1x(const float* __restrict__ x,
                                              const uint16_t* __restrict__ WfcB,
                                              const float* __restrict__ bfc,
                                              const uint16_t* __restrict__ WihB,
                                              const float* __restrict__ b_f,
                                              const float* __restrict__ b_b,
                                              uint16_t* __restrict__ Xp) {
    __shared__ float tile[64 * 65];
    __shared__ __align__(16) uint16_t As[8192];
    __shared__ __align__(16) uint16_t Bs[4224];
    __shared__ __align__(16) uint16_t Hs2[8432];

    const int bb = blockIdx.y, n0 = blockIdx.x * 64;
    const int tid = threadIdx.x, w = tid >> 6, l = tid & 63;
    const int lm = l & 15, lk = l >> 4;
    const float* xb = x + (size_t)bb * CF_ * T_;

    const int t4 = (tid & 15) * 4, cf_r = tid >> 4;
    const int kk = (tid & 15) * 4, t_r = tid >> 4;

    float4 xv0, xv1;
    {
        const float* p = &xb[(size_t)(0 + cf_r) * T_ + n0 + t4];
        xv0 = *(const float4*)p;
        xv1 = *(const float4*)(p + 32 * T_);
    }

    const int wmA = (w >> 1) * 32, wnA = (w & 1) * 32;
    floatx4 acc[2][2] = {};
    for (int k0 = 0; k0 < CF_; k0 += 64) {
        __syncthreads();
        tile[(t4 + 0) * 65 + cf_r] = xv0.x;
        tile[(t4 + 1) * 65 + cf_r] = xv0.y;
        tile[(t4 + 2) * 65 + cf_r] = xv0.z;
        tile[(t4 + 3) * 65 + cf_r] = xv0.w;
        tile[(t4 + 0) * 65 + cf_r + 32] = xv1.x;
        tile[(t4 + 1) * 65 + cf_r + 32] = xv1.y;
        tile[(t4 + 2) * 65 + cf_r + 32] = xv1.z;
        tile[(t4 + 3) * 65 + cf_r + 32] = xv1.w;
        gload16(WfcB + (size_t)l * CF_ + k0 + w * 8,        As + (w * 128 + l) * 8);
        gload16(WfcB + (size_t)(64 + l) * CF_ + k0 + w * 8, As + (w * 128 + 64 + l) * 8);
        __syncthreads();
        if (k0 + 64 < CF_) {
            const float* p = &xb[(size_t)(k0 + 64 + cf_r) * T_ + n0 + t4];
            xv0 = *(const float4*)p;
            xv1 = *(const float4*)(p + 32 * T_);
        }
        #pragma unroll
        for (int pass = 0; pass < 2; ++pass) {
            const int tr = t_r + pass * 32;
            ushort4 o;
            o.x = f_to_bf16(tile[tr * 65 + kk + 0]);
            o.y = f_to_bf16(tile[tr * 65 + kk + 1]);
            o.z = f_to_bf16(tile[tr * 65 + kk + 2]);
            o.w = f_to_bf16(tile[tr * 65 + kk + 3]);
            *(ushort4*)&Bs[((kk >> 3) * 66 + tr) * 8 + (kk & 7)] = o;
        }
        __syncthreads();
        short8 a[2][2], bfr[2][2];
        #pragma unroll
        for (int kf = 0; kf < 2; ++kf) {
            #pragma unroll
            for (int mf = 0; mf < 2; ++mf)
                a[mf][kf] = *(const short8*)&As[((kf * 4 + lk) * 128 + wmA + mf * 16 + lm) * 8];
            #pragma unroll
            for (int nf = 0; nf < 2; ++nf)
                bfr[nf][kf] = *(const short8*)&Bs[((kf * 4 + lk) * 66 + wnA + nf * 16 + lm) * 8];
        }
        #pragma unroll
        for (int mf = 0; mf < 2; ++mf)
            #pragma unroll
            for (int nf = 0; nf < 2; ++nf) {
                acc[mf][nf] = __builtin_amdgcn_mfma_f32_16x16x32_bf16(a[mf][0], bfr[nf][0], acc[mf][nf], 0, 0, 0);
                acc[mf][nf] = __builtin_amdgcn_mfma_f32_16x16x32_bf16(a[mf][1], bfr[nf][1], acc[mf][nf], 0, 0, 0);
            }
    }
    __syncthreads();
    #pragma unroll
    for (int mf = 0; mf < 2; ++mf) {
        const int d0 = wmA + mf * 16 + lk * 4;
        const float4 bv = *(const float4*)&bfc[d0];
        const int c = ((wmA + mf * 16) >> 3) + (lk >> 1);
        #pragma unroll
        for (int nf = 0; nf < 2; ++nf) {
            const int t = wnA + nf * 16 + lm;
            ushort4 o;
            o.x = f_to_bf16(acc[mf][nf][0] + bv.x);
            o.y = f_to_bf16(acc[mf][nf][1] + bv.y);
            o.z = f_to_bf16(acc[mf][nf][2] + bv.z);
            o.w = f_to_bf16(acc[mf][nf][3] + bv.w);
            *(ushort4*)&Hs2[(c * 66 + t) * 8 + (lk & 1) * 4] = o;
        }
    }
    __syncthreads();

    const int dirw = w >> 2;
    const int db   = dirw * B_ + bb;
    const uint16_t* Wp = WihB + (size_t)dirw * (G4_ * H_);
    const float* bi = dirw ? b_b : b_f;
    #pragma unroll
    for (int it = 0; it < 2; ++it) {
        const int gbase = (w & 3) * 64 + it * 256;
        short8 aw[4][4];
        #pragma unroll
        for (int mf = 0; mf < 4; ++mf)
            #pragma unroll
            for (int kf = 0; kf < 4; ++kf)
                aw[mf][kf] = *(const short8*)&Wp[(size_t)(gbase + mf * 16 + lm) * H_ + kf * 32 + lk * 8];
        floatx4 acc2[4][4] = {};
        #pragma unroll
        for (int nf = 0; nf < 4; ++nf) {
            short8 bbf[4];
            #pragma unroll
            for (int kf = 0; kf < 4; ++kf)
                bbf[kf] = *(const short8*)&Hs2[((kf * 4 + lk) * 66 + nf * 16 + lm) * 8];
            #pragma unroll
            for (int mf = 0; mf < 4; ++mf)
                #pragma unroll
                for (int kf = 0; kf < 4; ++kf)
                    acc2[mf][nf] = __builtin_amdgcn_mfma_f32_16x16x32_bf16(aw[mf][kf], bbf[kf], acc2[mf][nf], 0, 0, 0);
        }
        #pragma unroll
        for (int mf = 0; mf < 4; ++mf) {
            const int g0 = gbase + mf * 16 + lk * 4;
            const float4 bv = *(const float4*)&bi[g0];
            #pragma unroll
            for (int nf = 0; nf < 4; ++nf) {
                const int t = n0 + nf * 16 + lm;
                ushort4 o;
                o.x = f_to_bf16(acc2[mf][nf][0] + bv.x);
                o.y = f_to_bf16(acc2[mf][nf][1] + bv.y);
                o.z = f_to_bf16(acc2[mf][nf][2] + bv.z);
                o.w = f_to_bf16(acc2[mf][nf][3] + bv.w);
                *(ushort4*)&Xp[((size_t)db * T_ + t) * G4_ + g0] = o;
            }
        }
    }
}

// =====================================================================
// k_lstm: gate-sliced wave layout (round-3 version, verified win).
// =====================================================================
__global__ __launch_bounds__(512) void k_lstm(const uint16_t* __restrict__ Xp,
                                              const uint16_t* __restrict__ WhhB,
                                              uint16_t* __restrict__ hs) {
    __shared__ __align__(16) uint16_t h_sh[2][16 * 136];
    const int dir = blockIdx.y, t0 = blockIdx.x * 16;
    const int tid = threadIdx.x, w = tid >> 6, l = tid & 63;
    const int lm = l & 15, lk = l >> 4;
    const int gcol = w * 16 + lm;
    const int tloc = lk * 4;
    const uint16_t* Wp = WhhB + dir * (G4_ * H_);

    short8 bw[4][4];
    #pragma unroll
    for (int q = 0; q < 4; ++q)
        #pragma unroll
        for (int kf = 0; kf < 4; ++kf)
            bw[q][kf] = *(const short8*)&Wp[(size_t)(q * H_ + gcol) * H_ + kf * 32 + lk * 8];

    for (int i = tid; i < 16 * 136; i += 512) h_sh[0][i] = 0;
    float c[4] = {0.f, 0.f, 0.f, 0.f};

    uint16_t xva[4][4], xvb[4][4];
    {
        const int b0 = dir ? (B_ - 1) : 0;
        const uint16_t* xp = Xp + ((size_t)(dir * B_ + b0) * T_ + t0 + tloc) * G4_;
        #pragma unroll
        for (int r = 0; r < 4; ++r)
            #pragma unroll
            for (int q = 0; q < 4; ++q)
                xva[r][q] = xp[(size_t)r * G4_ + q * H_ + gcol];
    }
    bar_lds();

    auto step = [&](int s, uint16_t (&xc)[4][4], uint16_t (&xn)[4][4], int par) {
        const int b_idx = dir ? (B_ - 1 - s) : s;
        short8 af[4];
        #pragma unroll
        for (int kf = 0; kf < 4; ++kf)
            af[kf] = *(const short8*)&h_sh[par][lm * 136 + kf * 32 + lk * 8];
        floatx4 acc[4] = {};
        #pragma unroll
        for (int q = 0; q < 4; ++q)
            #pragma unroll
            for (int kf = 0; kf < 4; ++kf)
                acc[q] = __builtin_amdgcn_mfma_f32_16x16x32_bf16(af[kf], bw[q][kf], acc[q], 0, 0, 0);
        if (s < B_ - 1) {
            const int bn = dir ? (B_ - 2 - s) : (s + 1);
            const uint16_t* xp = Xp + ((size_t)(dir * B_ + bn) * T_ + t0 + tloc) * G4_;
            #pragma unroll
            for (int r = 0; r < 4; ++r)
                #pragma unroll
                for (int q = 0; q < 4; ++q)
                    xn[r][q] = xp[(size_t)r * G4_ + q * H_ + gcol];
        }
        #pragma unroll
        for (int r = 0; r < 4; ++r) {
            float zi = acc[0][r] + bf16_to_f(xc[r][0]);
            float zf = acc[1][r] + bf16_to_f(xc[r][1]);
            float zg = acc[2][r] + bf16_to_f(xc[r][2]);
            float zo = acc[3][r] + bf16_to_f(xc[r][3]);
            float si = rcpf(1.f + __builtin_amdgcn_exp2f(-LOG2E * zi));
            float sf = rcpf(1.f + __builtin_amdgcn_exp2f(-LOG2E * zf));
            float so = rcpf(1.f + __builtin_amdgcn_exp2f(-LOG2E * zo));
            float tg = 1.f - 2.f * rcpf(1.f + __builtin_amdgcn_exp2f(2.f * LOG2E * zg));
            c[r] = sf * c[r] + si * tg;
            float tc = 1.f - 2.f * rcpf(1.f + __builtin_amdgcn_exp2f(2.f * LOG2E * c[r]));
            float hn = so * tc;
            uint16_t hb = f_to_bf16(hn);
            h_sh[par ^ 1][(tloc + r) * 136 + gcol] = hb;
            hs[((size_t)b_idx * T_ + t0 + tloc + r) * 256 + dir * H_ + gcol] = hb;
        }
        bar_lds();
    };

    for (int s2 = 0; s2 < 16; ++s2) {
        step(2 * s2,     xva, xvb, 0);
        step(2 * s2 + 1, xvb, xva, 1);
    }
}

// =====================================================================
// k_outm: out[b][e][t] fp32 = W_out(128x256) @ hs[b]^T + b_out
// =====================================================================
__global__ __launch_bounds__(256) void k_outm(const uint16_t* __restrict__ WoutB,
                                              const uint16_t* __restrict__ hs,
                                              const float* __restrict__ bout,
                                              float* __restrict__ out) {
    __shared__ __align__(16) uint16_t As[4096], Bs[4096];
    const int b = blockIdx.z, m0 = blockIdx.y * 64, n0 = blockIdx.x * 64;
    const int tid = threadIdx.x, w = tid >> 6, l = tid & 63;
    const int wm = (w >> 1) * 32, wn = (w & 1) * 32;
    const int lm = l & 15, lk = l >> 4;
    const uint16_t* A = WoutB + (size_t)m0 * 256;
    const uint16_t* Bp = hs + ((size_t)b * T_ + n0) * 256;
    floatx4 acc[2][2] = {};
    const uint16_t* gA = A + (size_t)l * 256;
    const uint16_t* gB = Bp + (size_t)l * 256;
    for (int k0 = 0; k0 < 256; k0 += 64) {
        __syncthreads();
        gload16(gA + k0 + (2 * w) * 8,     As + ((2 * w) * 64 + l) * 8);
        gload16(gA + k0 + (2 * w + 1) * 8, As + ((2 * w + 1) * 64 + l) * 8);
        gload16(gB + k0 + (2 * w) * 8,     Bs + ((2 * w) * 64 + l) * 8);
        gload16(gB + k0 + (2 * w + 1) * 8, Bs + ((2 * w + 1) * 64 + l) * 8);
        __syncthreads();
        short8 a[2][2], bfr[2][2];
        #pragma unroll
        for (int kf = 0; kf < 2; ++kf) {
            #pragma unroll
            for (int mf = 0; mf < 2; ++mf)
                a[mf][kf] = *(const short8*)&As[((kf * 4 + lk) * 64 + wm + mf * 16 + lm) * 8];
            #pragma unroll
            for (int nf = 0; nf < 2; ++nf)
                bfr[nf][kf] = *(const short8*)&Bs[((kf * 4 + lk) * 64 + wn + nf * 16 + lm) * 8];
        }
        #pragma unroll
        for (int mf = 0; mf < 2; ++mf)
            #pragma unroll
            for (int nf = 0; nf < 2; ++nf) {
                acc[mf][nf] = __builtin_amdgcn_mfma_f32_16x16x32_bf16(a[mf][0], bfr[nf][0], acc[mf][nf], 0, 0, 0);
                acc[mf][nf] = __builtin_amdgcn_mfma_f32_16x16x32_bf16(a[mf][1], bfr[nf][1], acc[mf][nf], 0, 0, 0);
            }
    }
    #pragma unroll
    for (int mf = 0; mf < 2; ++mf) {
        const int e0 = m0 + wm + mf * 16 + lk * 4;
        const float4 bv = *(const float4*)&bout[e0];
        #pragma unroll
        for (int nf = 0; nf < 2; ++nf) {
            const int t = n0 + wn + nf * 16 + lm;
            out[((size_t)b * H_ + e0 + 0) * T_ + t] = acc[mf][nf][0] + bv.x;
            out[((size_t)b * H_ + e0 + 1) * T_ + t] = acc[mf][nf][1] + bv.y;
            out[((size_t)b * H_ + e0 + 2) * T_ + t] = acc[mf][nf][2] + bv.z;
            out[((size_t)b * H_ + e0 + 3) * T_ + t] = acc[mf][nf][3] + bv.w;
        }
    }
}

// =====================================================================
extern "C" void kernel_launch(void* const* d_in, const int* in_sizes, int n_in,
                              void* d_out, int out_size, void* d_ws, size_t ws_size,
                              hipStream_t stream) {
    const float* x     = (const float*)d_in[0];
    const float* Wfc   = (const float*)d_in[1];
    const float* bfc   = (const float*)d_in[2];
    const float* Wih_f = (const float*)d_in[3];
    const float* Whh_f = (const float*)d_in[4];
    const float* b_f   = (const float*)d_in[5];
    const float* Wih_b = (const float*)d_in[6];
    const float* Whh_b = (const float*)d_in[7];
    const float* b_b   = (const float*)d_in[8];
    const float* Wout  = (const float*)d_in[9];
    const float* bout  = (const float*)d_in[10];
    float* out = (float*)d_out;

    char* ws = (char*)d_ws;
    const size_t NEED_XT = 110166016;   // layout incl. 67 MB xT

    if (ws_size >= NEED_XT) {
        uint16_t* Xp    = (uint16_t*)(ws);                  // 33,554,432 B
        uint16_t* xT    = (uint16_t*)(ws + 33554432);       // 67,108,864 B
        uint16_t* hsB   = (uint16_t*)(ws + 100663296);      //  8,388,608 B
        uint16_t* WfcB  = (uint16_t*)(ws + 109051904);      //    524,288 B
        uint16_t* WihB  = (uint16_t*)(ws + 109576192);      //    262,144 B
        uint16_t* WhhB  = (uint16_t*)(ws + 109838336);      //    262,144 B
        uint16_t* WoutB = (uint16_t*)(ws + 110100480);      //     65,536 B

        k_cvt_all<<<dim3(544), 256, 0, stream>>>(Wfc, Wih_f, Wih_b, Whh_f, Whh_b, Wout,
                                                 WfcB, WihB, WhhB, WoutB);
        k_xt   <<<dim3(8, 32, 32), 256, 0, stream>>>(x, xT);
        k_fc1g <<<dim3(8, 32),   512, 0, stream>>>(xT, WfcB, bfc, WihB, b_f, b_b, Xp);
        k_lstm <<<dim3(32, 2),   512, 0, stream>>>(Xp, WhhB, hsB);
        k_outm <<<dim3(8, 2, 32), 256, 0, stream>>>(WoutB, hsB, bout, out);
    } else {
        uint16_t* Xp    = (uint16_t*)(ws);                  // 33,554,432 B
        uint16_t* hsB   = (uint16_t*)(ws + 33554432);       //  8,388,608 B
        uint16_t* WfcB  = (uint16_t*)(ws + 41943040);       //    524,288 B
        uint16_t* WihB  = (uint16_t*)(ws + 42467328);       //    262,144 B
        uint16_t* WhhB  = (uint16_t*)(ws + 42729472);       //    262,144 B
        uint16_t* WoutB = (uint16_t*)(ws + 42991616);       //     65,536 B

        k_cvt_all<<<dim3(544), 256, 0, stream>>>(Wfc, Wih_f, Wih_b, Whh_f, Whh_b, Wout,
                                                 WfcB, WihB, WhhB, WoutB);
        k_fc1x <<<dim3(8, 32),   512, 0, stream>>>(x, WfcB, bfc, WihB, b_f, b_b, Xp);
        k_lstm <<<dim3(32, 2),   512, 0, stream>>>(Xp, WhhB, hsB);
        k_outm <<<dim3(8, 2, 32), 256, 0, stream>>>(WoutB, hsB, bout, out);
    }
}

// Round 6
// 294.177 us; speedup vs baseline: 1.1075x; 1.1075x over previous
//
#include <hip/hip_runtime.h>
#include <stdint.h>

typedef __attribute__((ext_vector_type(8))) short short8;
typedef __attribute__((ext_vector_type(4))) float floatx4;

// ---------- helpers ----------
__device__ __forceinline__ float bf16_to_f(uint16_t u) {
    union { uint32_t i; float f; } v; v.i = ((uint32_t)u) << 16; return v.f;
}
__device__ __forceinline__ uint16_t f_to_bf16(float f) {
    union { uint32_t i; float f; } v; v.f = f;
    uint32_t u = v.i;
    u += 0x7FFFu + ((u >> 16) & 1u);   // round-to-nearest-even
    return (uint16_t)(u >> 16);
}
__device__ __forceinline__ void gload16(const void* g, void* l) {
    __builtin_amdgcn_global_load_lds(
        (const __attribute__((address_space(1))) void*)g,
        (__attribute__((address_space(3))) void*)l, 16, 0, 0);
}
__device__ __forceinline__ float rcpf(float x) { return __builtin_amdgcn_rcpf(x); }

// LDS-only barrier: waits own LDS ops, does NOT drain vmcnt.
__device__ __forceinline__ void bar_lds() {
    asm volatile("s_waitcnt lgkmcnt(0)" ::: "memory");
    __builtin_amdgcn_s_barrier();
    asm volatile("" ::: "memory");
}

#define B_  32
#define T_  512
#define CF_ 2048
#define H_  128
#define G4_ 512   // 4*H
#define LOG2E 1.4426950408889634f

// =====================================================================
// k_cvt_all: all 6 weight tensors fp32 -> bf16 in ONE launch.
// =====================================================================
__global__ __launch_bounds__(256) void k_cvt_all(
        const float* __restrict__ Wfc, const float* __restrict__ Wih_f,
        const float* __restrict__ Wih_b, const float* __restrict__ Whh_f,
        const float* __restrict__ Whh_b, const float* __restrict__ Wout,
        uint16_t* __restrict__ WfcB, uint16_t* __restrict__ WihB,
        uint16_t* __restrict__ WhhB, uint16_t* __restrict__ WoutB) {
    const int blk = blockIdx.x;
    const float* s; uint16_t* d; int off;
    if (blk < 256)      { s = Wfc;   d = WfcB;          off = blk; }
    else if (blk < 320) { s = Wih_f; d = WihB;          off = blk - 256; }
    else if (blk < 384) { s = Wih_b; d = WihB + 65536;  off = blk - 320; }
    else if (blk < 448) { s = Whh_f; d = WhhB;          off = blk - 384; }
    else if (blk < 512) { s = Whh_b; d = WhhB + 65536;  off = blk - 448; }
    else                { s = Wout;  d = WoutB;         off = blk - 512; }
    const int i = off * 1024 + threadIdx.x * 4;
    float4 v = *(const float4*)&s[i];
    ushort4 o;
    o.x = f_to_bf16(v.x); o.y = f_to_bf16(v.y);
    o.z = f_to_bf16(v.z); o.w = f_to_bf16(v.w);
    *(ushort4*)&d[i] = o;
}

// =====================================================================
// k_fc1r: fc1 + input-projection, BK=256 -> only 8 K-steps (evidence:
// per-iteration cost of the lockstep loop is ~structural-constant, so
// 4x fewer iterations ~= 4x less time).
// x transpose done IN REGISTERS: per pass a wave loads 4 cf-rows x 64 t
// (lane = t, fully coalesced 256 B fp32 loads), converts, and writes one
// ushort4 (4 cf at its t) into chunk-major bf16 Bs. No fp32 LDS tile.
// W staged via global_load_lds into As (chunk stride 1032 elems: +8 pad
// breaks the 2 KB-stride lk-group bank conflict of the old layout).
// Numerics identical to previous versions (same RTNE, same k-order).
// =====================================================================
__global__ __launch_bounds__(512) void k_fc1r(const float* __restrict__ x,
                                              const uint16_t* __restrict__ WfcB,
                                              const float* __restrict__ bfc,
                                              const uint16_t* __restrict__ WihB,
                                              const float* __restrict__ b_f,
                                              const float* __restrict__ b_b,
                                              uint16_t* __restrict__ Xp) {
    __shared__ __align__(16) uint16_t As[32 * 1032];   // 32 chunks x 128 rows x 8 (+8 pad)  66.0 KB
    __shared__ __align__(16) uint16_t Bs[32 * 66 * 8]; // 32 chunks x 66 t-slots x 8         33.8 KB
    __shared__ __align__(16) uint16_t Hs2[8432];       // Hfc chunk-major (stride 66)        16.9 KB

    const int bb = blockIdx.y, n0 = blockIdx.x * 64;
    const int tid = threadIdx.x, w = tid >> 6, l = tid & 63;
    const int lm = l & 15, lk = l >> 4;
    const float* xb = x + (size_t)bb * CF_ * T_;

    const int wmA = (w >> 1) * 32, wnA = (w & 1) * 32;
    floatx4 acc[2][2] = {};

    for (int kc = 0; kc < 8; ++kc) {
        const int k0 = kc * 256;
        __syncthreads();   // protect As/Bs against previous iter's frag reads
        // ---- W staging: 8 gload16/thread. Wave w stages chunks w*4..w*4+3,
        //      rows l and 64+l of each.
        #pragma unroll
        for (int j = 0; j < 4; ++j) {
            const int c = w * 4 + j;
            gload16(WfcB + (size_t)l * CF_ + k0 + c * 8,        As + c * 1032 + l * 8);
            gload16(WfcB + (size_t)(64 + l) * CF_ + k0 + c * 8, As + c * 1032 + (64 + l) * 8);
        }
        // ---- x register-transpose: wave w covers cf-rows k0+w*32 .. +31,
        //      all 64 t (lane = t). Loads first (latency pipelines), then cvt+write.
        float xr[8][4];
        #pragma unroll
        for (int p = 0; p < 8; ++p)
            #pragma unroll
            for (int i = 0; i < 4; ++i)
                xr[p][i] = xb[(size_t)(k0 + w * 32 + p * 4 + i) * T_ + n0 + l];
        #pragma unroll
        for (int p = 0; p < 8; ++p) {
            const int cf = w * 32 + p * 4;             // block-local cf (0..255)
            ushort4 o;
            o.x = f_to_bf16(xr[p][0]);
            o.y = f_to_bf16(xr[p][1]);
            o.z = f_to_bf16(xr[p][2]);
            o.w = f_to_bf16(xr[p][3]);
            *(ushort4*)&Bs[((cf >> 3) * 66 + l) * 8 + (cf & 7)] = o;
        }
        __syncthreads();   // all staging visible (drains vmcnt + lgkm)
        // ---- frags + MFMA: 8 k-fragments per iter
        #pragma unroll
        for (int kf = 0; kf < 8; ++kf) {
            const int ch = kf * 4 + lk;
            short8 a0 = *(const short8*)&As[ch * 1032 + (wmA + lm) * 8];
            short8 a1 = *(const short8*)&As[ch * 1032 + (wmA + 16 + lm) * 8];
            short8 b0 = *(const short8*)&Bs[(ch * 66 + wnA + lm) * 8];
            short8 b1 = *(const short8*)&Bs[(ch * 66 + wnA + 16 + lm) * 8];
            acc[0][0] = __builtin_amdgcn_mfma_f32_16x16x32_bf16(a0, b0, acc[0][0], 0, 0, 0);
            acc[0][1] = __builtin_amdgcn_mfma_f32_16x16x32_bf16(a0, b1, acc[0][1], 0, 0, 0);
            acc[1][0] = __builtin_amdgcn_mfma_f32_16x16x32_bf16(a1, b0, acc[1][0], 0, 0, 0);
            acc[1][1] = __builtin_amdgcn_mfma_f32_16x16x32_bf16(a1, b1, acc[1][1], 0, 0, 0);
        }
    }
    __syncthreads();
    // epilogue A: bias + bf16 -> Hs2 chunk-major (stride 66)
    #pragma unroll
    for (int mf = 0; mf < 2; ++mf) {
        const int d0 = wmA + mf * 16 + lk * 4;
        const float4 bv = *(const float4*)&bfc[d0];
        const int c = ((wmA + mf * 16) >> 3) + (lk >> 1);
        #pragma unroll
        for (int nf = 0; nf < 2; ++nf) {
            const int t = wnA + nf * 16 + lm;
            ushort4 o;
            o.x = f_to_bf16(acc[mf][nf][0] + bv.x);
            o.y = f_to_bf16(acc[mf][nf][1] + bv.y);
            o.z = f_to_bf16(acc[mf][nf][2] + bv.z);
            o.w = f_to_bf16(acc[mf][nf][3] + bv.w);
            *(ushort4*)&Hs2[(c * 66 + t) * 8 + (lk & 1) * 4] = o;
        }
    }
    __syncthreads();

    // ---------------- Phase B ----------------
    const int dirw = w >> 2;
    const int db   = dirw * B_ + bb;
    const uint16_t* Wp = WihB + (size_t)dirw * (G4_ * H_);
    const float* bi = dirw ? b_b : b_f;
    #pragma unroll
    for (int it = 0; it < 2; ++it) {
        const int gbase = (w & 3) * 64 + it * 256;
        short8 aw[4][4];
        #pragma unroll
        for (int mf = 0; mf < 4; ++mf)
            #pragma unroll
            for (int kf = 0; kf < 4; ++kf)
                aw[mf][kf] = *(const short8*)&Wp[(size_t)(gbase + mf * 16 + lm) * H_ + kf * 32 + lk * 8];
        floatx4 acc2[4][4] = {};
        #pragma unroll
        for (int nf = 0; nf < 4; ++nf) {
            short8 bbf[4];
            #pragma unroll
            for (int kf = 0; kf < 4; ++kf)
                bbf[kf] = *(const short8*)&Hs2[((kf * 4 + lk) * 66 + nf * 16 + lm) * 8];
            #pragma unroll
            for (int mf = 0; mf < 4; ++mf)
                #pragma unroll
                for (int kf = 0; kf < 4; ++kf)
                    acc2[mf][nf] = __builtin_amdgcn_mfma_f32_16x16x32_bf16(aw[mf][kf], bbf[kf], acc2[mf][nf], 0, 0, 0);
        }
        #pragma unroll
        for (int mf = 0; mf < 4; ++mf) {
            const int g0 = gbase + mf * 16 + lk * 4;
            const float4 bv = *(const float4*)&bi[g0];
            #pragma unroll
            for (int nf = 0; nf < 4; ++nf) {
                const int t = n0 + nf * 16 + lm;
                ushort4 o;
                o.x = f_to_bf16(acc2[mf][nf][0] + bv.x);
                o.y = f_to_bf16(acc2[mf][nf][1] + bv.y);
                o.z = f_to_bf16(acc2[mf][nf][2] + bv.z);
                o.w = f_to_bf16(acc2[mf][nf][3] + bv.w);
                *(ushort4*)&Xp[((size_t)db * T_ + t) * G4_ + g0] = o;
            }
        }
    }
}

// =====================================================================
// k_lstm: gate-sliced wave layout (round-3 version, verified win).
// =====================================================================
__global__ __launch_bounds__(512) void k_lstm(const uint16_t* __restrict__ Xp,
                                              const uint16_t* __restrict__ WhhB,
                                              uint16_t* __restrict__ hs) {
    __shared__ __align__(16) uint16_t h_sh[2][16 * 136];
    const int dir = blockIdx.y, t0 = blockIdx.x * 16;
    const int tid = threadIdx.x, w = tid >> 6, l = tid & 63;
    const int lm = l & 15, lk = l >> 4;
    const int gcol = w * 16 + lm;
    const int tloc = lk * 4;
    const uint16_t* Wp = WhhB + dir * (G4_ * H_);

    short8 bw[4][4];
    #pragma unroll
    for (int q = 0; q < 4; ++q)
        #pragma unroll
        for (int kf = 0; kf < 4; ++kf)
            bw[q][kf] = *(const short8*)&Wp[(size_t)(q * H_ + gcol) * H_ + kf * 32 + lk * 8];

    for (int i = tid; i < 16 * 136; i += 512) h_sh[0][i] = 0;
    float c[4] = {0.f, 0.f, 0.f, 0.f};

    uint16_t xva[4][4], xvb[4][4];
    {
        const int b0 = dir ? (B_ - 1) : 0;
        const uint16_t* xp = Xp + ((size_t)(dir * B_ + b0) * T_ + t0 + tloc) * G4_;
        #pragma unroll
        for (int r = 0; r < 4; ++r)
            #pragma unroll
            for (int q = 0; q < 4; ++q)
                xva[r][q] = xp[(size_t)r * G4_ + q * H_ + gcol];
    }
    bar_lds();

    auto step = [&](int s, uint16_t (&xc)[4][4], uint16_t (&xn)[4][4], int par) {
        const int b_idx = dir ? (B_ - 1 - s) : s;
        short8 af[4];
        #pragma unroll
        for (int kf = 0; kf < 4; ++kf)
            af[kf] = *(const short8*)&h_sh[par][lm * 136 + kf * 32 + lk * 8];
        floatx4 acc[4] = {};
        #pragma unroll
        for (int q = 0; q < 4; ++q)
            #pragma unroll
            for (int kf = 0; kf < 4; ++kf)
                acc[q] = __builtin_amdgcn_mfma_f32_16x16x32_bf16(af[kf], bw[q][kf], acc[q], 0, 0, 0);
        if (s < B_ - 1) {
            const int bn = dir ? (B_ - 2 - s) : (s + 1);
            const uint16_t* xp = Xp + ((size_t)(dir * B_ + bn) * T_ + t0 + tloc) * G4_;
            #pragma unroll
            for (int r = 0; r < 4; ++r)
                #pragma unroll
                for (int q = 0; q < 4; ++q)
                    xn[r][q] = xp[(size_t)r * G4_ + q * H_ + gcol];
        }
        #pragma unroll
        for (int r = 0; r < 4; ++r) {
            float zi = acc[0][r] + bf16_to_f(xc[r][0]);
            float zf = acc[1][r] + bf16_to_f(xc[r][1]);
            float zg = acc[2][r] + bf16_to_f(xc[r][2]);
            float zo = acc[3][r] + bf16_to_f(xc[r][3]);
            float si = rcpf(1.f + __builtin_amdgcn_exp2f(-LOG2E * zi));
            float sf = rcpf(1.f + __builtin_amdgcn_exp2f(-LOG2E * zf));
            float so = rcpf(1.f + __builtin_amdgcn_exp2f(-LOG2E * zo));
            float tg = 1.f - 2.f * rcpf(1.f + __builtin_amdgcn_exp2f(2.f * LOG2E * zg));
            c[r] = sf * c[r] + si * tg;
            float tc = 1.f - 2.f * rcpf(1.f + __builtin_amdgcn_exp2f(2.f * LOG2E * c[r]));
            float hn = so * tc;
            uint16_t hb = f_to_bf16(hn);
            h_sh[par ^ 1][(tloc + r) * 136 + gcol] = hb;
            hs[((size_t)b_idx * T_ + t0 + tloc + r) * 256 + dir * H_ + gcol] = hb;
        }
        bar_lds();
    };

    for (int s2 = 0; s2 < 16; ++s2) {
        step(2 * s2,     xva, xvb, 0);
        step(2 * s2 + 1, xvb, xva, 1);
    }
}

// =====================================================================
// k_outm: out[b][e][t] fp32 = W_out(128x256) @ hs[b]^T + b_out
// =====================================================================
__global__ __launch_bounds__(256) void k_outm(const uint16_t* __restrict__ WoutB,
                                              const uint16_t* __restrict__ hs,
                                              const float* __restrict__ bout,
                                              float* __restrict__ out) {
    __shared__ __align__(16) uint16_t As[4096], Bs[4096];
    const int b = blockIdx.z, m0 = blockIdx.y * 64, n0 = blockIdx.x * 64;
    const int tid = threadIdx.x, w = tid >> 6, l = tid & 63;
    const int wm = (w >> 1) * 32, wn = (w & 1) * 32;
    const int lm = l & 15, lk = l >> 4;
    const uint16_t* A = WoutB + (size_t)m0 * 256;
    const uint16_t* Bp = hs + ((size_t)b * T_ + n0) * 256;
    floatx4 acc[2][2] = {};
    const uint16_t* gA = A + (size_t)l * 256;
    const uint16_t* gB = Bp + (size_t)l * 256;
    for (int k0 = 0; k0 < 256; k0 += 64) {
        __syncthreads();
        gload16(gA + k0 + (2 * w) * 8,     As + ((2 * w) * 64 + l) * 8);
        gload16(gA + k0 + (2 * w + 1) * 8, As + ((2 * w + 1) * 64 + l) * 8);
        gload16(gB + k0 + (2 * w) * 8,     Bs + ((2 * w) * 64 + l) * 8);
        gload16(gB + k0 + (2 * w + 1) * 8, Bs + ((2 * w + 1) * 64 + l) * 8);
        __syncthreads();
        short8 a[2][2], bfr[2][2];
        #pragma unroll
        for (int kf = 0; kf < 2; ++kf) {
            #pragma unroll
            for (int mf = 0; mf < 2; ++mf)
                a[mf][kf] = *(const short8*)&As[((kf * 4 + lk) * 64 + wm + mf * 16 + lm) * 8];
            #pragma unroll
            for (int nf = 0; nf < 2; ++nf)
                bfr[nf][kf] = *(const short8*)&Bs[((kf * 4 + lk) * 64 + wn + nf * 16 + lm) * 8];
        }
        #pragma unroll
        for (int mf = 0; mf < 2; ++mf)
            #pragma unroll
            for (int nf = 0; nf < 2; ++nf) {
                acc[mf][nf] = __builtin_amdgcn_mfma_f32_16x16x32_bf16(a[mf][0], bfr[nf][0], acc[mf][nf], 0, 0, 0);
                acc[mf][nf] = __builtin_amdgcn_mfma_f32_16x16x32_bf16(a[mf][1], bfr[nf][1], acc[mf][nf], 0, 0, 0);
            }
    }
    #pragma unroll
    for (int mf = 0; mf < 2; ++mf) {
        const int e0 = m0 + wm + mf * 16 + lk * 4;
        const float4 bv = *(const float4*)&bout[e0];
        #pragma unroll
        for (int nf = 0; nf < 2; ++nf) {
            const int t = n0 + wn + nf * 16 + lm;
            out[((size_t)b * H_ + e0 + 0) * T_ + t] = acc[mf][nf][0] + bv.x;
            out[((size_t)b * H_ + e0 + 1) * T_ + t] = acc[mf][nf][1] + bv.y;
            out[((size_t)b * H_ + e0 + 2) * T_ + t] = acc[mf][nf][2] + bv.z;
            out[((size_t)b * H_ + e0 + 3) * T_ + t] = acc[mf][nf][3] + bv.w;
        }
    }
}

// =====================================================================
extern "C" void kernel_launch(void* const* d_in, const int* in_sizes, int n_in,
                              void* d_out, int out_size, void* d_ws, size_t ws_size,
                              hipStream_t stream) {
    const float* x     = (const float*)d_in[0];
    const float* Wfc   = (const float*)d_in[1];
    const float* bfc   = (const float*)d_in[2];
    const float* Wih_f = (const float*)d_in[3];
    const float* Whh_f = (const float*)d_in[4];
    const float* b_f   = (const float*)d_in[5];
    const float* Wih_b = (const float*)d_in[6];
    const float* Whh_b = (const float*)d_in[7];
    const float* b_b   = (const float*)d_in[8];
    const float* Wout  = (const float*)d_in[9];
    const float* bout  = (const float*)d_in[10];
    float* out = (float*)d_out;

    char* ws = (char*)d_ws;
    uint16_t* Xp    = (uint16_t*)(ws);                 // 33,554,432 B
    uint16_t* hsB   = (uint16_t*)(ws + 33554432);      //  8,388,608 B
    uint16_t* WfcB  = (uint16_t*)(ws + 41943040);      //    524,288 B
    uint16_t* WihB  = (uint16_t*)(ws + 42467328);      //    262,144 B
    uint16_t* WhhB  = (uint16_t*)(ws + 42729472);      //    262,144 B
    uint16_t* WoutB = (uint16_t*)(ws + 42991616);      //     65,536 B

    k_cvt_all<<<dim3(544), 256, 0, stream>>>(Wfc, Wih_f, Wih_b, Whh_f, Whh_b, Wout,
                                             WfcB, WihB, WhhB, WoutB);
    k_fc1r <<<dim3(8, 32),   512, 0, stream>>>(x, WfcB, bfc, WihB, b_f, b_b, Xp);
    k_lstm <<<dim3(32, 2),   512, 0, stream>>>(Xp, WhhB, hsB);
    k_outm <<<dim3(8, 2, 32), 256, 0, stream>>>(WoutB, hsB, bout, out);
}